// Round 3
// baseline (2773.119 us; speedup 1.0000x reference)
//
#include <hip/hip_runtime.h>
#include <math.h>

// Problem constants
#define DIMN   2048
#define NHEADS 16
#define HDIM   128
#define SEQ    2048
#define BATCH  2
#define MROWS  (BATCH*SEQ)   // 4096
#define SCALE  0.08838834764831845f  // 1/sqrt(128)
#define BHSD   (BATCH*NHEADS*SEQ*HDIM)  // 8388608

typedef unsigned short u16;
typedef unsigned short ushort8v __attribute__((ext_vector_type(8)));

__device__ inline float bf2f(u16 h) {
    union { unsigned u; float f; } v; v.u = ((unsigned)h) << 16; return v.f;
}
__device__ inline u16 f2bf(float f) {   // round-to-nearest-even bf16
    union { float f; unsigned u; } v; v.f = f;
    unsigned r = v.u + 0x7FFF + ((v.u >> 16) & 1);
    return (u16)(r >> 16);
}

// ---------------------------------------------------------------------------
// RoPE tables, compact [SEQ][64] (apply-kernel only reads the low half).
// Replicates numpy fp32 pipeline: inv_freq fp32, freq = fp32(t)*inv_freq,
// correctly-rounded cos/sin via double.
__global__ __launch_bounds__(64) void rope_table_kernel(float* __restrict__ cosT,
                                                        float* __restrict__ sinT) {
    int pos = blockIdx.x;      // 0..2047
    int i   = threadIdx.x;     // 0..63
    double e    = (double)(2 * i) / 128.0;
    float  invf = (float)pow(10000.0, -e);
    float  freq = (float)pos * invf;          // fp32 multiply, matches np.outer
    double fr = (double)freq;
    cosT[pos*64 + i] = (float)cos(fr);
    sinT[pos*64 + i] = (float)sin(fr);
}

// ---------------------------------------------------------------------------
// GEMM: C[M,N] = A[M,K] * W[N,K]^T, 128x128 tile, BK=32, 8x8 micro-tile,
// prefetch-pipelined. fp32 compute in LDS.
// MODE 0: A fp32 (x), outputs bf16 scattered into q/k/v [B,H,S,D].
// MODE 1: A bf16 (attention out), output fp32 row-major (d_out).
template<int MODE>
__global__ __launch_bounds__(256) void gemm128(const void* __restrict__ Av,
                                               const float* __restrict__ W,
                                               void* __restrict__ o0,
                                               void* __restrict__ o1,
                                               void* __restrict__ o2,
                                               int K) {
    __shared__ __align__(16) float As[32][132];   // transposed: As[k][m]
    __shared__ __align__(16) float Bs[32][132];   // transposed: Bs[k][n]

    const int tid  = threadIdx.x;
    const int row  = tid >> 1;            // 0..127 (staging row)
    const int cseg = (tid & 1) * 16;      // 0 or 16 (staging k-segment)
    const int tx   = tid & 15;
    const int ty   = tid >> 4;
    const int bx   = blockIdx.x;
    const int by   = blockIdx.y;

    const float* aRowF = (const float*)Av + (long)(by*128 + row) * K;  // MODE 0
    const u16*   aRowH = (const u16*)Av   + (long)(by*128 + row) * K;  // MODE 1
    const float* bRow  = W + (long)(bx*128 + row) * K;

    float acc[8][8];
    #pragma unroll
    for (int i = 0; i < 8; ++i)
        #pragma unroll
        for (int j = 0; j < 8; ++j) acc[i][j] = 0.0f;

    // Prologue: load k-tile 0
    float4 av[4]; ushort8v ah[2]; float4 bv[4];
    if constexpr (MODE == 0) {
        #pragma unroll
        for (int j = 0; j < 4; ++j) av[j] = *(const float4*)(aRowF + cseg + 4*j);
    } else {
        #pragma unroll
        for (int j = 0; j < 2; ++j) ah[j] = *(const ushort8v*)(aRowH + cseg + 8*j);
    }
    #pragma unroll
    for (int j = 0; j < 4; ++j) bv[j] = *(const float4*)(bRow + cseg + 4*j);

    for (int k0 = 0; k0 < K; k0 += 32) {
        __syncthreads();   // previous tile's compute done
        if constexpr (MODE == 0) {
            #pragma unroll
            for (int j = 0; j < 4; ++j) {
                As[cseg+4*j+0][row] = av[j].x; As[cseg+4*j+1][row] = av[j].y;
                As[cseg+4*j+2][row] = av[j].z; As[cseg+4*j+3][row] = av[j].w;
            }
        } else {
            #pragma unroll
            for (int j = 0; j < 2; ++j)
                #pragma unroll
                for (int e = 0; e < 8; ++e)
                    As[cseg+8*j+e][row] = bf2f(ah[j][e]);
        }
        #pragma unroll
        for (int j = 0; j < 4; ++j) {
            Bs[cseg+4*j+0][row] = bv[j].x; Bs[cseg+4*j+1][row] = bv[j].y;
            Bs[cseg+4*j+2][row] = bv[j].z; Bs[cseg+4*j+3][row] = bv[j].w;
        }
        __syncthreads();   // tile staged

        // Prefetch next k-tile (latency hides under the FMA block below)
        if (k0 + 32 < K) {
            if constexpr (MODE == 0) {
                #pragma unroll
                for (int j = 0; j < 4; ++j)
                    av[j] = *(const float4*)(aRowF + k0 + 32 + cseg + 4*j);
            } else {
                #pragma unroll
                for (int j = 0; j < 2; ++j)
                    ah[j] = *(const ushort8v*)(aRowH + k0 + 32 + cseg + 8*j);
            }
            #pragma unroll
            for (int j = 0; j < 4; ++j)
                bv[j] = *(const float4*)(bRow + k0 + 32 + cseg + 4*j);
        }

        #pragma unroll 4
        for (int k = 0; k < 32; ++k) {
            float4 t0 = *(const float4*)&As[k][ty*4];
            float4 t1 = *(const float4*)&As[k][64 + ty*4];
            float4 t2 = *(const float4*)&Bs[k][tx*4];
            float4 t3 = *(const float4*)&Bs[k][64 + tx*4];
            float a[8] = {t0.x,t0.y,t0.z,t0.w, t1.x,t1.y,t1.z,t1.w};
            float b[8] = {t2.x,t2.y,t2.z,t2.w, t3.x,t3.y,t3.z,t3.w};
            #pragma unroll
            for (int i = 0; i < 8; ++i)
                #pragma unroll
                for (int j = 0; j < 8; ++j)
                    acc[i][j] = fmaf(a[i], b[j], acc[i][j]);
        }
    }

    // Epilogue
    if constexpr (MODE == 0) {
        // column block bx covers qkv cols [bx*128, bx*128+128): t = bx/16, h = bx%16
        const int t = bx >> 4;
        const int h = bx & 15;
        const int b = by >> 4;                 // M = 4096 = 2*2048, tiles align
        const int sbase = (by & 15) << 7;      // s offset within batch
        u16* dst = (t == 0) ? (u16*)o0 : (t == 1) ? (u16*)o1 : (u16*)o2;
        const long hb = ((long)(b*NHEADS + h)) * SEQ * HDIM;
        #pragma unroll
        for (int i = 0; i < 8; ++i) {
            int r = (i < 4) ? (ty*4 + i) : (64 + ty*4 + i - 4);
            long ro = hb + (long)(sbase + r) * HDIM;
            ushort4 lo, hi;
            lo.x=f2bf(acc[i][0]); lo.y=f2bf(acc[i][1]); lo.z=f2bf(acc[i][2]); lo.w=f2bf(acc[i][3]);
            hi.x=f2bf(acc[i][4]); hi.y=f2bf(acc[i][5]); hi.z=f2bf(acc[i][6]); hi.w=f2bf(acc[i][7]);
            *(ushort4*)&dst[ro + tx*4]      = lo;
            *(ushort4*)&dst[ro + 64 + tx*4] = hi;
        }
    } else {
        float* out = (float*)o0;
        #pragma unroll
        for (int i = 0; i < 8; ++i) {
            int r  = (i < 4) ? (ty*4 + i) : (64 + ty*4 + i - 4);
            long gm = (long)(by*128 + r);
            float4 lo = make_float4(acc[i][0], acc[i][1], acc[i][2], acc[i][3]);
            float4 hi = make_float4(acc[i][4], acc[i][5], acc[i][6], acc[i][7]);
            *(float4*)&out[gm*DIMN + bx*128 + tx*4]      = lo;
            *(float4*)&out[gm*DIMN + bx*128 + 64 + tx*4] = hi;
        }
    }
}

// ---------------------------------------------------------------------------
// In-place RoPE on bf16 q and k ([B,H,S,D]). Tables are [SEQ][64] fp32.
__global__ __launch_bounds__(256) void rope_apply_kernel(u16* __restrict__ q,
                                                         u16* __restrict__ k,
                                                         const float* __restrict__ cosT,
                                                         const float* __restrict__ sinT) {
    int idx = blockIdx.x * 256 + threadIdx.x;   // 0 .. B*H*S*64-1
    int i  = idx & 63;
    int s  = (idx >> 6) & (SEQ - 1);
    int bh = idx >> 17;
    long base = ((long)bh * SEQ + s) * HDIM;
    float c  = cosT[s*64 + i];
    float sn = sinT[s*64 + i];
    float q1 = bf2f(q[base + i]), q2 = bf2f(q[base + 64 + i]);
    q[base + i]      = f2bf(q1 * c - q2 * sn);
    q[base + 64 + i] = f2bf(q2 * c + q1 * sn);
    float k1 = bf2f(k[base + i]), k2 = bf2f(k[base + 64 + i]);
    k[base + i]      = f2bf(k1 * c - k2 * sn);
    k[base + 64 + i] = f2bf(k2 * c + k1 * sn);
}

// ---------------------------------------------------------------------------
// Flash attention, fp32 compute, bf16 I/O. QT=64 q-rows per block, KT=32 keys.
// 256 threads: score thread (tx,ty) owns rows ty*4..ty*4+3, cols {tx*2, tx*2+1}.
// PV: same rows, d-cols {tx*4+j} and {64+tx*4+j}.
__global__ __launch_bounds__(256) void attn_kernel(const u16* __restrict__ qb,
                                                   const u16* __restrict__ kb,
                                                   const u16* __restrict__ vb,
                                                   u16* __restrict__ ao) {
    __shared__ __align__(16) float Qst[128][68];  // Qst[d][r]
    __shared__ __align__(16) float Kst[128][36];  // Kst[d][j]
    __shared__ __align__(16) float Vs[32][132];   // Vs[j][d]
    __shared__ __align__(16) float Pst[32][68];   // Pst[j][r]

    const int tid = threadIdx.x;
    const int tx  = tid & 15;
    const int ty  = tid >> 4;
    const int bq  = blockIdx.x;
    const int h   = blockIdx.y;
    const int b   = blockIdx.z;
    const int q0  = bq * 64;

    const long headoff = ((long)(b*NHEADS + h)) * SEQ * HDIM;
    const u16* qh = qb + headoff;
    const u16* kh = kb + headoff;
    const u16* vh = vb + headoff;

    // Stage Q transposed (once per block)
    {
        int qrow = tid & 63;
        int qseg = (tid >> 6) * 32;
        const u16* src = qh + (long)(q0 + qrow) * HDIM + qseg;
        #pragma unroll
        for (int j = 0; j < 4; ++j) {
            ushort8v v = *(const ushort8v*)(src + 8*j);
            #pragma unroll
            for (int e = 0; e < 8; ++e)
                Qst[qseg + 8*j + e][qrow] = bf2f(v[e]);
        }
    }

    float m[4], l[4], acc[4][8];
    #pragma unroll
    for (int i = 0; i < 4; ++i) {
        m[i] = -1e30f; l[i] = 0.0f;
        #pragma unroll
        for (int j = 0; j < 8; ++j) acc[i][j] = 0.0f;
    }

    const int ntiles = (q0 + 64) >> 5;   // 2*bq + 2
    for (int t = 0; t < ntiles; ++t) {
        const int kt0 = t * 32;
        __syncthreads();  // prev PV done (and Q staged, first iter)

        // Stage K transposed and V row-major
        {
            int krow = tid & 31;
            int dseg = (tid >> 5) * 16;
            const u16* src = kh + (long)(kt0 + krow) * HDIM + dseg;
            #pragma unroll
            for (int j = 0; j < 2; ++j) {
                ushort8v v = *(const ushort8v*)(src + 8*j);
                #pragma unroll
                for (int e = 0; e < 8; ++e)
                    Kst[dseg + 8*j + e][krow] = bf2f(v[e]);
            }
            int vrow = tid >> 3;
            int vseg = (tid & 7) * 16;
            const u16* vsrc = vh + (long)(kt0 + vrow) * HDIM + vseg;
            #pragma unroll
            for (int j = 0; j < 2; ++j) {
                ushort8v v = *(const ushort8v*)(vsrc + 8*j);
                float4 f0 = make_float4(bf2f(v[0]), bf2f(v[1]), bf2f(v[2]), bf2f(v[3]));
                float4 f1 = make_float4(bf2f(v[4]), bf2f(v[5]), bf2f(v[6]), bf2f(v[7]));
                *(float4*)&Vs[vrow][vseg + 8*j]     = f0;
                *(float4*)&Vs[vrow][vseg + 8*j + 4] = f1;
            }
        }
        __syncthreads();

        // Scores: sc[i][j] = q(ty*4+i) . k(tx*2+j)
        float sc[4][2] = {{0,0},{0,0},{0,0},{0,0}};
        #pragma unroll 4
        for (int d = 0; d < 128; ++d) {
            float4 qv = *(const float4*)&Qst[d][ty*4];
            float2 kv = *(const float2*)&Kst[d][tx*2];
            float qa[4] = {qv.x, qv.y, qv.z, qv.w};
            #pragma unroll
            for (int i = 0; i < 4; ++i) {
                sc[i][0] = fmaf(qa[i], kv.x, sc[i][0]);
                sc[i][1] = fmaf(qa[i], kv.y, sc[i][1]);
            }
        }
        // scale + causal mask
        #pragma unroll
        for (int i = 0; i < 4; ++i) {
            int rg = q0 + ty*4 + i;
            #pragma unroll
            for (int j = 0; j < 2; ++j) {
                int kg = kt0 + tx*2 + j;
                float v = sc[i][j] * SCALE;
                sc[i][j] = (kg > rg) ? -1e30f : v;
            }
        }
        // online softmax update (row reduce across the 16 tx lanes)
        float p[4][2];
        #pragma unroll
        for (int i = 0; i < 4; ++i) {
            float pm = fmaxf(sc[i][0], sc[i][1]);
            #pragma unroll
            for (int o = 1; o < 16; o <<= 1) pm = fmaxf(pm, __shfl_xor(pm, o, 64));
            float mn = fmaxf(m[i], pm);
            float ef = expf(m[i] - mn);
            p[i][0] = expf(sc[i][0] - mn);
            p[i][1] = expf(sc[i][1] - mn);
            float rs = p[i][0] + p[i][1];
            #pragma unroll
            for (int o = 1; o < 16; o <<= 1) rs += __shfl_xor(rs, o, 64);
            l[i] = l[i] * ef + rs;
            m[i] = mn;
            #pragma unroll
            for (int j = 0; j < 8; ++j) acc[i][j] *= ef;
            Pst[tx*2 + 0][ty*4 + i] = p[i][0];
            Pst[tx*2 + 1][ty*4 + i] = p[i][1];
        }
        __syncthreads();

        // PV: acc[i][:] += sum_kj P[kj][row] * V[kj][d]
        #pragma unroll 4
        for (int kj = 0; kj < 32; ++kj) {
            float4 pv  = *(const float4*)&Pst[kj][ty*4];
            float4 vlo = *(const float4*)&Vs[kj][tx*4];
            float4 vhi = *(const float4*)&Vs[kj][64 + tx*4];
            float pa[4] = {pv.x, pv.y, pv.z, pv.w};
            float vl[4] = {vlo.x, vlo.y, vlo.z, vlo.w};
            float vh2[4] = {vhi.x, vhi.y, vhi.z, vhi.w};
            #pragma unroll
            for (int i = 0; i < 4; ++i) {
                #pragma unroll
                for (int j = 0; j < 4; ++j) {
                    acc[i][j]     = fmaf(pa[i], vl[j],  acc[i][j]);
                    acc[i][4 + j] = fmaf(pa[i], vh2[j], acc[i][4 + j]);
                }
            }
        }
    }

    // Write output (bf16) in [B,S,H*D] layout (feeds the out-projection GEMM)
    #pragma unroll
    for (int i = 0; i < 4; ++i) {
        float inv = 1.0f / l[i];
        long ro = ((long)b * SEQ + q0 + ty*4 + i) * DIMN + h * HDIM;
        ushort4 lo, hi;
        lo.x=f2bf(acc[i][0]*inv); lo.y=f2bf(acc[i][1]*inv);
        lo.z=f2bf(acc[i][2]*inv); lo.w=f2bf(acc[i][3]*inv);
        hi.x=f2bf(acc[i][4]*inv); hi.y=f2bf(acc[i][5]*inv);
        hi.z=f2bf(acc[i][6]*inv); hi.w=f2bf(acc[i][7]*inv);
        *(ushort4*)&ao[ro + tx*4]      = lo;
        *(ushort4*)&ao[ro + 64 + tx*4] = hi;
    }
}

// ---------------------------------------------------------------------------
// ws layout (65 MB total — previous 136 MB overflowed ws_size and corrupted
// adjacent allocations, causing the deterministic post-timing divergence):
//   cosT  [2048][64] fp32   0.5 MB
//   sinT  [2048][64] fp32   0.5 MB
//   qb,kb,vb [B,H,S,D] bf16 16 MB each
//   ao    [B,S,H*D]   bf16  16 MB
extern "C" void kernel_launch(void* const* d_in, const int* in_sizes, int n_in,
                              void* d_out, int out_size, void* d_ws, size_t ws_size,
                              hipStream_t stream) {
    const float* x     = (const float*)d_in[0];
    const float* qkv_w = (const float*)d_in[1];
    const float* out_w = (const float*)d_in[2];
    float* out = (float*)d_out;
    float* ws  = (float*)d_ws;

    float* cosT = ws;
    float* sinT = ws + SEQ*64;
    u16* qb = (u16*)(ws + 2*SEQ*64);
    u16* kb = qb + BHSD;
    u16* vb = kb + BHSD;
    u16* ao = vb + BHSD;

    rope_table_kernel<<<dim3(SEQ), dim3(64), 0, stream>>>(cosT, sinT);

    // QKV projection + scatter to [B,H,S,D] (bf16)
    gemm128<0><<<dim3(48, 32), dim3(256), 0, stream>>>(x, qkv_w, qb, kb, vb, DIMN);

    // RoPE in-place on q,k
    rope_apply_kernel<<<dim3((BATCH*NHEADS*SEQ*64)/256), dim3(256), 0, stream>>>(qb, kb, cosT, sinT);

    // Flash attention
    attn_kernel<<<dim3(SEQ/64, NHEADS, BATCH), dim3(256), 0, stream>>>(qb, kb, vb, ao);

    // Output projection (bf16 A, fp32 W/out)
    gemm128<1><<<dim3(16, 32), dim3(256), 0, stream>>>(ao, out_w, out, nullptr, nullptr, DIMN);
}

// Round 4
// 759.664 us; speedup vs baseline: 3.6505x; 3.6505x over previous
//
#include <hip/hip_runtime.h>
#include <math.h>

// Problem constants
#define DIMN   2048
#define NHEADS 16
#define HDIM   128
#define SEQ    2048
#define BATCH  2
#define SCALE  0.08838834764831845f  // 1/sqrt(128)
#define BHSD   (BATCH*NHEADS*SEQ*HDIM)  // 8388608

typedef unsigned short u16;
typedef __attribute__((ext_vector_type(8))) unsigned short ushort8v;
typedef __attribute__((ext_vector_type(8))) short bf16x8;   // MFMA A/B frag (8 bf16)
typedef __attribute__((ext_vector_type(4))) float f32x4;    // MFMA C/D frag

#define MFMA16(a,b,c) __builtin_amdgcn_mfma_f32_16x16x32_bf16(a,b,c,0,0,0)

__device__ inline float bf2f(u16 h) {
    union { unsigned u; float f; } v; v.u = ((unsigned)h) << 16; return v.f;
}
__device__ inline u16 f2bf(float f) {   // round-to-nearest-even bf16
    union { float f; unsigned u; } v; v.f = f;
    unsigned r = v.u + 0x7FFF + ((v.u >> 16) & 1);
    return (u16)(r >> 16);
}
__device__ inline ushort8v pack8(const float4& a, const float4& b) {
    ushort8v r;
    r[0]=f2bf(a.x); r[1]=f2bf(a.y); r[2]=f2bf(a.z); r[3]=f2bf(a.w);
    r[4]=f2bf(b.x); r[5]=f2bf(b.y); r[6]=f2bf(b.z); r[7]=f2bf(b.w);
    return r;
}

// ---------------------------------------------------------------------------
// RoPE tables, compact [SEQ][64]. numpy fp32 pipeline, correctly-rounded trig.
__global__ __launch_bounds__(64) void rope_table_kernel(float* __restrict__ cosT,
                                                        float* __restrict__ sinT) {
    int pos = blockIdx.x;
    int i   = threadIdx.x;
    double e    = (double)(2 * i) / 128.0;
    float  invf = (float)pow(10000.0, -e);
    float  freq = (float)pos * invf;
    double fr = (double)freq;
    cosT[pos*64 + i] = (float)cos(fr);
    sinT[pos*64 + i] = (float)sin(fr);
}

// ---------------------------------------------------------------------------
// MFMA bf16 GEMM: C[M,N] = A[M,K] * W[N,K]^T. 128x128 tile, BK=32.
// 4 waves, each computes 64x64 = 4x4 frags of 16x16 via mfma_f32_16x16x32_bf16.
// A/B staged to LDS as bf16 (fp32 inputs converted in-flight).
// Frag layout: A/B lane l -> row/col (l&15), k=(l>>4)*8+e (contiguous b128 read).
// C/D: col=lane&15, row=(lane>>4)*4+reg.
// MODE 0: A fp32 (x), scatter bf16 into q/k/v [B,H,S,D].
// MODE 1: A bf16 (attn out), output fp32 row-major (d_out).
template<int MODE>
__global__ __launch_bounds__(256) void gemm_mfma(const void* __restrict__ Av,
                                                 const float* __restrict__ W,
                                                 void* __restrict__ o0,
                                                 void* __restrict__ o1,
                                                 void* __restrict__ o2,
                                                 int K) {
    __shared__ __align__(16) u16 Alds[128][40];   // [m][k], 80B rows (16B-aligned)
    __shared__ __align__(16) u16 Blds[128][40];   // [n][k]

    const int tid  = threadIdx.x;
    const int srow = tid >> 1;            // staging row 0..127
    const int skk  = (tid & 1) * 16;      // staging k-segment
    const int w    = tid >> 6;            // wave 0..3
    const int l    = tid & 63;
    const int lr   = l & 15;
    const int lk   = l >> 4;
    const int wr   = (w >> 1) * 64;       // wave row offset in tile
    const int wc   = (w & 1) * 64;        // wave col offset
    const int bx   = blockIdx.x;
    const int by   = blockIdx.y;

    const float* aF = (const float*)Av + (long)(by*128 + srow) * K;
    const u16*   aH = (const u16*)Av   + (long)(by*128 + srow) * K;
    const float* bF = W + (long)(bx*128 + srow) * K;

    f32x4 acc[4][4];
    #pragma unroll
    for (int i = 0; i < 4; ++i)
        #pragma unroll
        for (int j = 0; j < 4; ++j) acc[i][j] = f32x4{0.f,0.f,0.f,0.f};

    // Prologue: load k-tile 0 into regs
    float4 av[4]; ushort8v ah[2]; float4 bv[4];
    if constexpr (MODE == 0) {
        #pragma unroll
        for (int j = 0; j < 4; ++j) av[j] = *(const float4*)(aF + skk + 4*j);
    } else {
        #pragma unroll
        for (int j = 0; j < 2; ++j) ah[j] = *(const ushort8v*)(aH + skk + 8*j);
    }
    #pragma unroll
    for (int j = 0; j < 4; ++j) bv[j] = *(const float4*)(bF + skk + 4*j);

    for (int k0 = 0; k0 < K; k0 += 32) {
        __syncthreads();   // previous tile's frag reads done
        if constexpr (MODE == 0) {
            *(ushort8v*)&Alds[srow][skk]     = pack8(av[0], av[1]);
            *(ushort8v*)&Alds[srow][skk + 8] = pack8(av[2], av[3]);
        } else {
            *(ushort8v*)&Alds[srow][skk]     = ah[0];
            *(ushort8v*)&Alds[srow][skk + 8] = ah[1];
        }
        *(ushort8v*)&Blds[srow][skk]     = pack8(bv[0], bv[1]);
        *(ushort8v*)&Blds[srow][skk + 8] = pack8(bv[2], bv[3]);
        __syncthreads();   // tile staged

        // Prefetch next k-tile (global latency hides under MFMAs)
        if (k0 + 32 < K) {
            if constexpr (MODE == 0) {
                #pragma unroll
                for (int j = 0; j < 4; ++j) av[j] = *(const float4*)(aF + k0+32 + skk + 4*j);
            } else {
                #pragma unroll
                for (int j = 0; j < 2; ++j) ah[j] = *(const ushort8v*)(aH + k0+32 + skk + 8*j);
            }
            #pragma unroll
            for (int j = 0; j < 4; ++j) bv[j] = *(const float4*)(bF + k0+32 + skk + 4*j);
        }

        // Compute: 8 ds_read_b128 + 16 MFMA per wave
        bf16x8 af[4], bf[4];
        #pragma unroll
        for (int mr = 0; mr < 4; ++mr)
            af[mr] = *(const bf16x8*)&Alds[wr + mr*16 + lr][lk*8];
        #pragma unroll
        for (int nr = 0; nr < 4; ++nr)
            bf[nr] = *(const bf16x8*)&Blds[wc + nr*16 + lr][lk*8];
        #pragma unroll
        for (int mr = 0; mr < 4; ++mr)
            #pragma unroll
            for (int nr = 0; nr < 4; ++nr)
                acc[mr][nr] = MFMA16(af[mr], bf[nr], acc[mr][nr]);
    }

    // Epilogue. C row = wr+mr*16+lk*4+reg, col = wc+nr*16+lr.
    if constexpr (MODE == 0) {
        const int t = bx >> 4;      // 0=q 1=k 2=v
        const int h = bx & 15;
        u16* dst = (t == 0) ? (u16*)o0 : (t == 1) ? (u16*)o1 : (u16*)o2;
        #pragma unroll
        for (int mr = 0; mr < 4; ++mr)
            #pragma unroll
            for (int r = 0; r < 4; ++r) {
                int m = by*128 + wr + mr*16 + lk*4 + r;
                int b = m >> 11, s = m & 2047;
                long ro = ((long)(b*NHEADS + h) * SEQ + s) * HDIM;
                #pragma unroll
                for (int nr = 0; nr < 4; ++nr)
                    dst[ro + wc + nr*16 + lr] = f2bf(acc[mr][nr][r]);
            }
    } else {
        float* out = (float*)o0;
        #pragma unroll
        for (int mr = 0; mr < 4; ++mr)
            #pragma unroll
            for (int r = 0; r < 4; ++r) {
                long m = by*128 + wr + mr*16 + lk*4 + r;
                #pragma unroll
                for (int nr = 0; nr < 4; ++nr)
                    out[m*DIMN + bx*128 + wc + nr*16 + lr] = acc[mr][nr][r];
            }
    }
}

// ---------------------------------------------------------------------------
// In-place RoPE on bf16 q and k ([B,H,S,D]). Tables [SEQ][64] fp32.
__global__ __launch_bounds__(256) void rope_apply_kernel(u16* __restrict__ q,
                                                         u16* __restrict__ k,
                                                         const float* __restrict__ cosT,
                                                         const float* __restrict__ sinT) {
    int idx = blockIdx.x * 256 + threadIdx.x;
    int i  = idx & 63;
    int s  = (idx >> 6) & (SEQ - 1);
    int bh = idx >> 17;
    long base = ((long)bh * SEQ + s) * HDIM;
    float c  = cosT[s*64 + i];
    float sn = sinT[s*64 + i];
    float q1 = bf2f(q[base + i]), q2 = bf2f(q[base + 64 + i]);
    q[base + i]      = f2bf(q1 * c - q2 * sn);
    q[base + 64 + i] = f2bf(q2 * c + q1 * sn);
    float k1 = bf2f(k[base + i]), k2 = bf2f(k[base + 64 + i]);
    k[base + i]      = f2bf(k1 * c - k2 * sn);
    k[base + 64 + i] = f2bf(k2 * c + k1 * sn);
}

// ---------------------------------------------------------------------------
// Flash attention with MFMA. QBLK=64 q-rows/block (16/wave), KT=32 keys/tile.
// QK^T: Q A-frags in regs (loaded once); K row-major in LDS read as B-frags.
// Softmax: 16-lane shuffle reduce; P staged bf16 through LDS (transposed).
// PV: P A-frag + transposed-V B-frags. Heavy blocks (large bq) launch first.
__global__ __launch_bounds__(256) void attn_mfma(const u16* __restrict__ qb,
                                                 const u16* __restrict__ kb,
                                                 const u16* __restrict__ vb,
                                                 u16* __restrict__ ao) {
    __shared__ __align__(16) u16 Klds[32][136];  // [key][d] 272B rows
    __shared__ __align__(16) u16 Vt[128][40];    // [d][key] 80B rows
    __shared__ __align__(16) u16 Pst[64][40];    // [q][key] bf16

    const int tid = threadIdx.x;
    const int w   = tid >> 6;
    const int l   = tid & 63;
    const int lr  = l & 15;
    const int lk  = l >> 4;
    const int bq  = (SEQ/64 - 1) - blockIdx.x;   // heavy blocks first
    const int h   = blockIdx.y;
    const int b   = blockIdx.z;
    const int q0  = bq * 64;

    const long headoff = ((long)(b*NHEADS + h)) * SEQ * HDIM;
    const u16* qh = qb + headoff;
    const u16* kh = kb + headoff;
    const u16* vh = vb + headoff;

    // Q A-frags: wave w owns q-rows q0+w*16..+15. Lane: row lr, k-slice lk*8.
    bf16x8 qf[4];
    {
        const u16* qrow = qh + (long)(q0 + w*16 + lr) * HDIM;
        #pragma unroll
        for (int ds = 0; ds < 4; ++ds)
            qf[ds] = *(const bf16x8*)(qrow + ds*32 + lk*8);
    }

    f32x4 accO[8];
    #pragma unroll
    for (int nb = 0; nb < 8; ++nb) accO[nb] = f32x4{0.f,0.f,0.f,0.f};
    float m_[4], l_[4];
    #pragma unroll
    for (int r = 0; r < 4; ++r) { m_[r] = -1e30f; l_[r] = 0.f; }

    const int srow = tid >> 3;           // staging: key row 0..31
    const int sd   = (tid & 7) * 16;     // d-segment

    const int ntiles = 2*bq + 2;
    for (int t = 0; t < ntiles; ++t) {
        const int kt0 = t * 32;
        __syncthreads();  // prev tile's LDS reads done

        // Stage K row-major + V transposed
        {
            const u16* ksrc = kh + (long)(kt0 + srow) * HDIM + sd;
            ushort8v k0v = *(const ushort8v*)ksrc;
            ushort8v k1v = *(const ushort8v*)(ksrc + 8);
            *(ushort8v*)&Klds[srow][sd]     = k0v;
            *(ushort8v*)&Klds[srow][sd + 8] = k1v;
            const u16* vsrc = vh + (long)(kt0 + srow) * HDIM + sd;
            ushort8v v0 = *(const ushort8v*)vsrc;
            ushort8v v1 = *(const ushort8v*)(vsrc + 8);
            #pragma unroll
            for (int e = 0; e < 8; ++e) Vt[sd + e][srow]     = v0[e];
            #pragma unroll
            for (int e = 0; e < 8; ++e) Vt[sd + 8 + e][srow] = v1[e];
        }
        __syncthreads();

        // QK^T: S[16q x 32k] per wave = 2 frags x 4 chained MFMAs
        f32x4 sv[2];
        #pragma unroll
        for (int kbk = 0; kbk < 2; ++kbk) {
            sv[kbk] = f32x4{0.f,0.f,0.f,0.f};
            #pragma unroll
            for (int ds = 0; ds < 4; ++ds) {
                bf16x8 kf = *(const bf16x8*)&Klds[kbk*16 + lr][ds*32 + lk*8];
                sv[kbk] = MFMA16(qf[ds], kf, sv[kbk]);
            }
        }

        // scale + causal mask (only last 2 tiles need the mask)
        const bool masked = (t >= 2*bq);
        #pragma unroll
        for (int kbk = 0; kbk < 2; ++kbk)
            #pragma unroll
            for (int r = 0; r < 4; ++r) {
                float v = sv[kbk][r] * SCALE;
                if (masked) {
                    int kg = kt0 + kbk*16 + lr;
                    int rg = q0 + w*16 + lk*4 + r;
                    if (kg > rg) v = -1e30f;
                }
                sv[kbk][r] = v;
            }

        // online softmax (rows live across 16 lanes sharing lk; reduce over lr)
        #pragma unroll
        for (int r = 0; r < 4; ++r) {
            float mx = fmaxf(sv[0][r], sv[1][r]);
            #pragma unroll
            for (int o = 1; o < 16; o <<= 1) mx = fmaxf(mx, __shfl_xor(mx, o, 64));
            float mn = fmaxf(m_[r], mx);
            float ef = expf(m_[r] - mn);
            float p0 = expf(sv[0][r] - mn);
            float p1 = expf(sv[1][r] - mn);
            float rs = p0 + p1;
            #pragma unroll
            for (int o = 1; o < 16; o <<= 1) rs += __shfl_xor(rs, o, 64);
            l_[r] = l_[r] * ef + rs;
            m_[r] = mn;
            #pragma unroll
            for (int nb = 0; nb < 8; ++nb) accO[nb][r] *= ef;
            int qrow = w*16 + lk*4 + r;
            Pst[qrow][lr]      = f2bf(p0);
            Pst[qrow][16 + lr] = f2bf(p1);
        }
        __syncthreads();

        // PV: O[16q x 128d] += P[16x32] . V[32x128]
        bf16x8 pf = *(const bf16x8*)&Pst[w*16 + lr][lk*8];
        #pragma unroll
        for (int nb = 0; nb < 8; ++nb) {
            bf16x8 vf = *(const bf16x8*)&Vt[nb*16 + lr][lk*8];
            accO[nb] = MFMA16(pf, vf, accO[nb]);
        }
    }

    // Write O (bf16) in [B,S,H*D]
    #pragma unroll
    for (int r = 0; r < 4; ++r) {
        float inv = 1.0f / l_[r];
        long ro = ((long)b * SEQ + q0 + w*16 + lk*4 + r) * DIMN + h * HDIM;
        #pragma unroll
        for (int nb = 0; nb < 8; ++nb)
            ao[ro + nb*16 + lr] = f2bf(accO[nb][r] * inv);
    }
}

// ---------------------------------------------------------------------------
// ws layout (65 MB): cosT/sinT [2048][64] fp32; qb,kb,vb [B,H,S,D] bf16;
// ao [B,S,H*D] bf16. (136 MB overflowed ws_size in R2 — keep under 65 MB.)
extern "C" void kernel_launch(void* const* d_in, const int* in_sizes, int n_in,
                              void* d_out, int out_size, void* d_ws, size_t ws_size,
                              hipStream_t stream) {
    const float* x     = (const float*)d_in[0];
    const float* qkv_w = (const float*)d_in[1];
    const float* out_w = (const float*)d_in[2];
    float* out = (float*)d_out;
    float* ws  = (float*)d_ws;

    float* cosT = ws;
    float* sinT = ws + SEQ*64;
    u16* qb = (u16*)(ws + 2*SEQ*64);
    u16* kb = qb + BHSD;
    u16* vb = kb + BHSD;
    u16* ao = vb + BHSD;

    rope_table_kernel<<<dim3(SEQ), dim3(64), 0, stream>>>(cosT, sinT);

    // QKV projection (MFMA) + scatter to [B,H,S,D] bf16
    gemm_mfma<0><<<dim3(48, 32), dim3(256), 0, stream>>>(x, qkv_w, qb, kb, vb, DIMN);

    // RoPE in-place on q,k
    rope_apply_kernel<<<dim3((BATCH*NHEADS*SEQ*64)/256), dim3(256), 0, stream>>>(qb, kb, cosT, sinT);

    // Flash attention (MFMA)
    attn_mfma<<<dim3(SEQ/64, NHEADS, BATCH), dim3(256), 0, stream>>>(qb, kb, vb, ao);

    // Output projection (MFMA, bf16 A, fp32 out)
    gemm_mfma<1><<<dim3(16, 32), dim3(256), 0, stream>>>(ao, out_w, out, nullptr, nullptr, DIMN);
}